// Round 11
// baseline (163.045 us; speedup 1.0000x reference)
//
#include <hip/hip_runtime.h>

// VQ-VAE VectorQuantizer forward, fp32, MI355X.
// B=64, C=D=64, H=W=32 -> N=65536 pixels, K=1024 codes.
// Outputs (flat concat): [0] loss, [1..4194305) quantized BCHW, [4194305..) indices (as float)
//
// R11: R10's inner loop (x in LDS, e on scalar path, 2 px/lane — VALU stream
// ~92% pure FMA) + K split ACROSS BLOCKS to restore occupancy.
// R10 post-mortem: limiter was stall, not issue — 512 blocks = 2 blocks/CU =
// ~2 waves/SIMD couldn't hide the per-group s_load drain. Now grid =
// (512 tiles, 2 K-halves) = 1024 blocks -> 3-4 blocks/CU (24+ waves/CU).
// Wave w of half h owns codes [h*512 + w*64, +64). Both halves compute
// bit-identical xsq (same code+data), per-block results go to ws, and a tiny
// merge kernel combines ascending-half with strict '<' == global
// first-occurrence argmin. Scalar e-traffic unchanged.
// Per-code arithmetic BIT-IDENTICAL to R0-R10 (passed, absmax 3.8e-6):
// pairwise-8 x_sq (fp-contract off), sequential d-ascending fp32 FMA dot,
// dist = (x_sq - 2*dot) + e_sq, strict-< ascending-k argmin, ascending merge.

#define KCODES 1024
#define DDIM   64
#define NPIX   65536        // B*H*W
#define QELEMS 4194304      // B*C*H*W
#define IDX_OFF (1 + QELEMS)
#define NWAVE  8            // waves per block
#define NHALF  2            // K-halves (blocks per pixel-tile)
#define CHUNK  (KCODES / (NWAVE * NHALF))   // 64 codes per wave
#define PXB    128          // pixels per block (2 per lane)

// ---------------- e_sq precompute: replicate np.sum(e*e, axis=1) pairwise-8 ----------------
__global__ void __launch_bounds__(256) esq_kernel(const float* __restrict__ e,
                                                  float* __restrict__ esq) {
    int k = blockIdx.x * 256 + threadIdx.x;
    if (k >= KCODES) return;
    {
#pragma clang fp contract(off)
        const float* row = e + k * DDIM;
        float r[8];
#pragma unroll
        for (int j = 0; j < 8; ++j) r[j] = row[j] * row[j];
#pragma unroll
        for (int i = 1; i < 8; ++i) {
#pragma unroll
            for (int j = 0; j < 8; ++j) {
                float v = row[i * 8 + j];
                r[j] += v * v;
            }
        }
        esq[k] = ((r[0] + r[1]) + (r[2] + r[3])) + ((r[4] + r[5]) + (r[6] + r[7]));
    }
}

// ---------------- main distance + argmin kernel ----------------
// Grid (512, 2): blockIdx.x = 128-pixel tile, blockIdx.y = K-half.
// Block = 512 threads = 8 waves. Wave w: codes [half*512 + w*64, +64) for all
// 128 pixels; lane l owns pixels tile*128+l and tile*128+l+64.
__global__ void __launch_bounds__(512) argmin_kernel(const float* __restrict__ x,
                                                     const float* __restrict__ e,
                                                     const float* __restrict__ esq,
                                                     float* __restrict__ best_ws,
                                                     int* __restrict__ idxh_ws) {
    __shared__ float x_lds[DDIM][PXB];   // [d][px], 32KB
    __shared__ float sbest[NWAVE][PXB];
    __shared__ int   sidx[NWAVE][PXB];

    const int w = __builtin_amdgcn_readfirstlane(threadIdx.x >> 6);
    const int l = threadIdx.x & 63;
    const int half = blockIdx.y;
    const int b = (blockIdx.x * PXB) >> 10;      // same b for whole tile (128-aligned)
    const int p0 = (blockIdx.x * PXB) & 1023;

    // stage x tile: 64 d-rows x 128 px, coalesced 512B rows
    {
        const float* xg = x + (size_t)b * 65536 + p0;
        for (int t = threadIdx.x; t < DDIM * PXB; t += 512)
            x_lds[t >> 7][t & 127] = xg[(size_t)(t >> 7) * 1024 + (t & 127)];
    }
    __syncthreads();

    // x_sq: EXACT numpy pairwise-8 (rounded products, no contraction), from LDS.
    // Identical code+data in both halves -> bit-identical xsq -> cross-half
    // distance comparisons are exact.
    float xsq0, xsq1;
    {
#pragma clang fp contract(off)
        float r0[8], r1[8];
#pragma unroll
        for (int j = 0; j < 8; ++j) {
            float v0 = x_lds[j][l];      r0[j] = v0 * v0;
            float v1 = x_lds[j][l + 64]; r1[j] = v1 * v1;
        }
#pragma unroll
        for (int ii = 1; ii < 8; ++ii) {
#pragma unroll
            for (int j = 0; j < 8; ++j) {
                float v0 = x_lds[ii * 8 + j][l];      r0[j] += v0 * v0;
                float v1 = x_lds[ii * 8 + j][l + 64]; r1[j] += v1 * v1;
            }
        }
        xsq0 = ((r0[0] + r0[1]) + (r0[2] + r0[3])) + ((r0[4] + r0[5]) + (r0[6] + r0[7]));
        xsq1 = ((r1[0] + r1[1]) + (r1[2] + r1[3])) + ((r1[4] + r1[5]) + (r1[6] + r1[7]));
    }

    float best0 = 3.4e38f, best1 = 3.4e38f;
    int bidx0 = 0, bidx1 = 0;
    const int kbeg = half * (KCODES / NHALF) + w * CHUNK;   // uniform (SGPR)

#pragma unroll 1
    for (int k = kbeg; k < kbeg + CHUNK; k += 8) {
        const float* e0 = e + (size_t)k * DDIM;   // uniform -> s_load batches
        float a[8], c[8];
#pragma unroll
        for (int j = 0; j < 8; ++j) { a[j] = 0.f; c[j] = 0.f; }
        // d-quads; per code per pixel the chain stays exactly d-ascending (d = 4q + m).
#pragma unroll
        for (int q = 0; q < 16; ++q) {
            const float xv0 = x_lds[4 * q + 0][l];
            const float xv1 = x_lds[4 * q + 1][l];
            const float xv2 = x_lds[4 * q + 2][l];
            const float xv3 = x_lds[4 * q + 3][l];
            const float yv0 = x_lds[4 * q + 0][l + 64];
            const float yv1 = x_lds[4 * q + 1][l + 64];
            const float yv2 = x_lds[4 * q + 2][l + 64];
            const float yv3 = x_lds[4 * q + 3][l + 64];
#pragma unroll
            for (int j = 0; j < 8; ++j) {
                const float e_0 = e0[j * 64 + 4 * q + 0];
                const float e_1 = e0[j * 64 + 4 * q + 1];
                const float e_2 = e0[j * 64 + 4 * q + 2];
                const float e_3 = e0[j * 64 + 4 * q + 3];
                a[j] = __builtin_fmaf(xv0, e_0, a[j]);
                a[j] = __builtin_fmaf(xv1, e_1, a[j]);
                a[j] = __builtin_fmaf(xv2, e_2, a[j]);
                a[j] = __builtin_fmaf(xv3, e_3, a[j]);
                c[j] = __builtin_fmaf(yv0, e_0, c[j]);
                c[j] = __builtin_fmaf(yv1, e_1, c[j]);
                c[j] = __builtin_fmaf(yv2, e_2, c[j]);
                c[j] = __builtin_fmaf(yv3, e_3, c[j]);
            }
        }

        // dist = (x_sq - 2*dot) + e_sq; strict < , ascending k (per pixel independently)
#pragma unroll
        for (int j = 0; j < 8; ++j) {
            const float qj = esq[k + j];
            const float s = (xsq0 - 2.0f * a[j]) + qj;
            if (s < best0) { best0 = s; bidx0 = k + j; }
            const float t = (xsq1 - 2.0f * c[j]) + qj;
            if (t < best1) { best1 = t; bidx1 = k + j; }
        }
    }

    // merge the 8 wave-chunks (ascending k within this half) via LDS
    sbest[w][l] = best0;        sbest[w][l + 64] = best1;
    sidx[w][l] = bidx0;         sidx[w][l + 64] = bidx1;
    __syncthreads();
    if (threadIdx.x < PXB) {
        const int t = threadIdx.x;
        float bb = sbest[0][t];
        int bi = sidx[0][t];
#pragma unroll
        for (int c2 = 1; c2 < NWAVE; ++c2) {
            float v = sbest[c2][t];
            if (v < bb) { bb = v; bi = sidx[c2][t]; }
        }
        const int gi = blockIdx.x * PXB + t;
        best_ws[half * NPIX + gi] = bb;
        idxh_ws[half * NPIX + gi] = bi;
    }
}

// ---------------- cross-half merge: ascending half + strict '<' ----------------
__global__ void __launch_bounds__(256) merge_kernel(const float* __restrict__ best_ws,
                                                    const int* __restrict__ idxh_ws,
                                                    int* __restrict__ idx_out,
                                                    float* __restrict__ out) {
    const int i = blockIdx.x * 256 + threadIdx.x;
    float b0 = best_ws[i];
    int i0 = idxh_ws[i];
    float b1 = best_ws[NPIX + i];
    int i1 = idxh_ws[NPIX + i];
    int bi = (b1 < b0) ? i1 : i0;   // strict < : half0 wins ties (lower k)
    idx_out[i] = bi;
    out[IDX_OFF + i] = (float)bi;   // harness reads d_out as float32
}

// ---------------- gather + transpose + per-block loss partials ----------------
// block = one (b,d) plane of 1024 pixels; coalesced read/write.
__global__ void __launch_bounds__(256) gather_kernel(const float* __restrict__ x,
                                                     const float* __restrict__ e,
                                                     const int* __restrict__ idx,
                                                     float* __restrict__ out,
                                                     float* __restrict__ partial) {
    const int bd = blockIdx.x;          // = b*64 + d
    const int b = bd >> 6;
    const int d = bd & 63;
    const size_t base = (size_t)bd * 1024;
    const int* idxb = idx + b * 1024;

    float acc = 0.f;
#pragma unroll
    for (int j = 0; j < 4; ++j) {
        int p = threadIdx.x + j * 256;
        int k = idxb[p];
        float ev = e[k * 64 + d];
        float xv = x[base + p];
        out[1 + base + p] = ev;         // quantized (straight-through == codebook value)
        float df = ev - xv;
        acc = __builtin_fmaf(df, df, acc);
    }
    __shared__ float sm[256];
    sm[threadIdx.x] = acc;
    __syncthreads();
    for (int s = 128; s > 0; s >>= 1) {
        if (threadIdx.x < s) sm[threadIdx.x] += sm[threadIdx.x + s];
        __syncthreads();
    }
    if (threadIdx.x == 0) partial[bd] = sm[0];
}

// ---------------- deterministic loss finalize ----------------
__global__ void __launch_bounds__(256) loss_kernel(const float* __restrict__ partial,
                                                   float* __restrict__ out) {
    float acc = 0.f;
    for (int i = threadIdx.x; i < 4096; i += 256) acc += partial[i];
    __shared__ float sm[256];
    sm[threadIdx.x] = acc;
    __syncthreads();
    for (int s = 128; s > 0; s >>= 1) {
        if (threadIdx.x < s) sm[threadIdx.x] += sm[threadIdx.x + s];
        __syncthreads();
    }
    // loss = q_latent + 0.25*e_latent = 1.25 * mean(diff^2)
    if (threadIdx.x == 0) out[0] = sm[0] * (1.25f / 4194304.f);
}

extern "C" void kernel_launch(void* const* d_in, const int* in_sizes, int n_in,
                              void* d_out, int out_size, void* d_ws, size_t ws_size,
                              hipStream_t stream) {
    const float* x = (const float*)d_in[0];   // [64,64,32,32]
    const float* e = (const float*)d_in[1];   // [1024,64]
    float* out = (float*)d_out;

    // ws layout: esq 4KB | best_ws float[2][65536] 512KB | idxh_ws int[2][65536] 512KB
    //            | idx int[65536] 256KB | partial 16KB   (total ~1.3MB)
    char* wsb = (char*)d_ws;
    float* esq     = (float*)wsb;
    float* best_ws = (float*)(wsb + 4096);
    int*   idxh_ws = (int*)(wsb + 4096 + 2 * NPIX * 4);
    int*   idx     = (int*)(wsb + 4096 + 4 * NPIX * 4);
    float* partial = (float*)(wsb + 4096 + 5 * NPIX * 4);

    esq_kernel<<<4, 256, 0, stream>>>(e, esq);
    argmin_kernel<<<dim3(NPIX / PXB, NHALF), 512, 0, stream>>>(x, e, esq, best_ws, idxh_ws);
    merge_kernel<<<NPIX / 256, 256, 0, stream>>>(best_ws, idxh_ws, idx, out);
    gather_kernel<<<4096, 256, 0, stream>>>(x, e, idx, out, partial);
    loss_kernel<<<1, 256, 0, stream>>>(partial, out);
}